// Round 8
// baseline (238.744 us; speedup 1.0000x reference)
//
#include <hip/hip_runtime.h>
#include <math.h>

// Problem constants
#define B_ 2
#define S_ 2048
#define D_ 1024
#define H_ 16
#define HKV_ 4
#define HD_ 64
#define SD_ 16

typedef __attribute__((ext_vector_type(8))) short bf16x8;
typedef __attribute__((ext_vector_type(4))) float f32x4;
typedef __attribute__((ext_vector_type(8))) unsigned short us8;
typedef __attribute__((ext_vector_type(4))) unsigned short us4;

#define LOG2E 1.4426950408889634f

__device__ __forceinline__ unsigned short f2bf(float f) {
  unsigned int u = __builtin_bit_cast(unsigned int, f);
  u += 0x7fffu + ((u >> 16) & 1u);   // RNE; inputs are finite
  return (unsigned short)(u >> 16);
}
__device__ __forceinline__ float bf2f(unsigned short x) {
  return __builtin_bit_cast(float, (unsigned int)x << 16);
}

// global -> LDS async DMA, 16B per lane; LDS dest wave-uniform base + lane*16.
__device__ __forceinline__ void gload16(const unsigned short* g, unsigned short* l) {
  __builtin_amdgcn_global_load_lds(
      (const __attribute__((address_space(1))) unsigned int*)g,
      (__attribute__((address_space(3))) unsigned int*)l, 16, 0, 0);
}

// ---------------------------------------------------------------------------
// Kernel 0: fp32 -> bf16 convert for GEMM operands. Also zeroes the attn
// work-stealing counter (runs first on the stream; re-zeroed every launch).
// ---------------------------------------------------------------------------
__global__ __launch_bounds__(256) void convert_bf16(
    const float* __restrict__ x, const float* __restrict__ wq,
    const float* __restrict__ wk, const float* __restrict__ wv,
    const float* __restrict__ wo, unsigned short* __restrict__ xb,
    unsigned short* __restrict__ wqkv, unsigned short* __restrict__ wob,
    int* __restrict__ ctr) {
  const int blk = blockIdx.x;
  if (blk == 0 && threadIdx.x == 0) *ctr = 0;
  const float* src;
  unsigned short* dst;
  int off;
  if (blk < 2048)      { src = x;  dst = xb;             off = blk * 2048; }
  else if (blk < 2560) { src = wq; dst = wqkv;           off = (blk - 2048) * 2048; }
  else if (blk < 2688) { src = wk; dst = wqkv + 1048576; off = (blk - 2560) * 2048; }
  else if (blk < 2816) { src = wv; dst = wqkv + 1310720; off = (blk - 2688) * 2048; }
  else                 { src = wo; dst = wob;            off = (blk - 2816) * 2048; }
  const int i = off + threadIdx.x * 8;
  float4 a = *(const float4*)(src + i);
  float4 b = *(const float4*)(src + i + 4);
  us8 o;
  o[0] = f2bf(a.x); o[1] = f2bf(a.y); o[2] = f2bf(a.z); o[3] = f2bf(a.w);
  o[4] = f2bf(b.x); o[5] = f2bf(b.y); o[6] = f2bf(b.z); o[7] = f2bf(b.w);
  *(us8*)(dst + i) = o;
}

// ---------------------------------------------------------------------------
// Kernel A/D: bf16 MFMA GEMM, m97 staging, 64x128 tile.
// C[m,n] = sum_k A[m,k]*Bm[n,k] (+ bias[n]); K=1024; 4 waves each 64x32.
// ---------------------------------------------------------------------------
__global__ __launch_bounds__(256) void gemm_bf16(
    const unsigned short* __restrict__ A, const unsigned short* __restrict__ Bm,
    const float* __restrict__ bias, float* __restrict__ C, int N) {
  __shared__ unsigned short As[64 * 64];
  __shared__ unsigned short Bs[128 * 64];
  const int tid = threadIdx.x;
  const int w = tid >> 6, lane = tid & 63;
  const int nm = lane & 15, quad = lane >> 4;
  const int m0 = blockIdx.y * 64, n0 = blockIdx.x * 128;
  const int wn = w * 32;

  f32x4 acc[4][2] = {};
  int arow[2], acol[2], brow[4], bcol[4];
#pragma unroll
  for (int it = 0; it < 2; ++it) {
    int s = it * 256 + tid;
    arow[it] = s >> 3;
    acol[it] = ((s & 7) ^ (arow[it] & 7)) * 8;
  }
#pragma unroll
  for (int it = 0; it < 4; ++it) {
    int s = it * 256 + tid;
    brow[it] = s >> 3;
    bcol[it] = ((s & 7) ^ (brow[it] & 7)) * 8;
  }

  for (int k0 = 0; k0 < 1024; k0 += 64) {
    __syncthreads();
#pragma unroll
    for (int it = 0; it < 2; ++it)
      gload16(A + (size_t)(m0 + arow[it]) * 1024 + k0 + acol[it],
              &As[(it * 256 + w * 64) * 8]);
#pragma unroll
    for (int it = 0; it < 4; ++it)
      gload16(Bm + (size_t)(n0 + brow[it]) * 1024 + k0 + bcol[it],
              &Bs[(it * 256 + w * 64) * 8]);
    __syncthreads();

#pragma unroll
    for (int ks = 0; ks < 2; ++ks) {
      const int cq = ks * 4 + quad;
      bf16x8 af[4], bfr[2];
#pragma unroll
      for (int mi = 0; mi < 4; ++mi) {
        const int m = mi * 16 + nm;
        af[mi] = *(const bf16x8*)&As[(m * 8 + (cq ^ (m & 7))) * 8];
      }
#pragma unroll
      for (int ni = 0; ni < 2; ++ni) {
        const int n = wn + ni * 16 + nm;
        bfr[ni] = *(const bf16x8*)&Bs[(n * 8 + (cq ^ (n & 7))) * 8];
      }
#pragma unroll
      for (int mi = 0; mi < 4; ++mi)
#pragma unroll
        for (int ni = 0; ni < 2; ++ni)
          acc[mi][ni] = __builtin_amdgcn_mfma_f32_16x16x32_bf16(
              af[mi], bfr[ni], acc[mi][ni], 0, 0, 0);
    }
  }

  float bv[2] = {0.f, 0.f};
  if (bias) {
#pragma unroll
    for (int ni = 0; ni < 2; ++ni) bv[ni] = bias[n0 + wn + ni * 16 + nm];
  }
#pragma unroll
  for (int mi = 0; mi < 4; ++mi) {
#pragma unroll
    for (int r = 0; r < 4; ++r) {
      const int row = m0 + mi * 16 + quad * 4 + r;
      float* crow = C + (size_t)row * N + n0 + wn + nm;
#pragma unroll
      for (int ni = 0; ni < 2; ++ni) crow[ni * 16] = acc[mi][ni][r] + bv[ni];
    }
  }
}

// ---------------------------------------------------------------------------
// Kernel B: RoPE + scatter (bf16) + low-rank sparsity proj (slots 0..19).
// q scaled by log2e/8, qsp by log2e/4 so attn uses native exp2.
// ---------------------------------------------------------------------------
__global__ __launch_bounds__(256) void rope_scatter(
    const float* __restrict__ P, const float* __restrict__ Ws,
    const float* __restrict__ bs, unsigned short* __restrict__ qh,
    unsigned short* __restrict__ kh, unsigned short* __restrict__ qsp,
    unsigned short* __restrict__ ksp) {
  __shared__ float wsl[16 * 64];
  __shared__ float bsl[16];
  __shared__ float rbuf[4][64];
  const int tid = threadIdx.x;
  const int row = blockIdx.x;
  const int b = row >> 11;
  const int s = row & 2047;
  {
    *(float4*)&wsl[tid * 4] = *(const float4*)&Ws[tid * 4];
    if (tid < 16) bsl[tid] = bs[tid];
  }
  __syncthreads();
  const int w = tid >> 6, lane = tid & 63;
  const int i = lane & 31, halfu = lane >> 5;
  const float theta = powf(10000.f, -((float)(2 * i) * (1.f / 64.f)));
  const float f = (float)s * theta;
  const float cf = cosf(f);
  const float sf = sinf(f);
  for (int slot = w; slot < 20; slot += 4) {
    float val = P[(size_t)row * 1536 + slot * 64 + lane];
    float partner = __shfl_xor(val, 32);
    float rot = halfu ? partner : -partner;
    float r = val * cf + rot * sf;
    unsigned short* dst;
    unsigned short* spdst;
    float qscale, spscale;
    if (slot < 16) {
      dst = qh + ((size_t)(b * 16 + slot) * 2048 + s) * 64;
      spdst = qsp + ((size_t)(b * 16 + slot) * 2048 + s) * 16;
      qscale = 0.125f * LOG2E; spscale = 0.25f * LOG2E;
    } else {
      int hh = slot - 16;
      dst = kh + ((size_t)(b * 4 + hh) * 2048 + s) * 64;
      spdst = ksp + ((size_t)(b * 4 + hh) * 2048 + s) * 16;
      qscale = 1.f; spscale = 1.f;
    }
    dst[lane] = f2bf(r * qscale);
    rbuf[w][lane] = r;
    int p = lane >> 4, j = lane & 15;
    float partial = 0.f;
#pragma unroll
    for (int t = 0; t < 16; ++t)
      partial += wsl[j * 64 + p * 16 + t] * rbuf[w][p * 16 + t];
    partial += __shfl_xor(partial, 16);
    partial += __shfl_xor(partial, 32);
    if (p == 0) spdst[j] = f2bf((partial + bsl[j]) * spscale);
  }
}

// ---------------------------------------------------------------------------
// Kernel B2: one-time V transpose: proj v-cols (f32) -> vt[bkv][d=64][s=2048] bf16.
// ---------------------------------------------------------------------------
__global__ __launch_bounds__(256) void v_transpose(
    const float* __restrict__ proj, unsigned short* __restrict__ vt) {
  __shared__ unsigned short t_[64 * 72];
  const int bkv = blockIdx.y;
  const int s0 = blockIdx.x * 64;
  const int b = bkv >> 2, hkv = bkv & 3;
  const int tid = threadIdx.x;
  const int sl = tid >> 2;
  const int c0 = (tid & 3) * 16;
  const float* src = proj + ((size_t)b * 2048 + s0 + sl) * 1536 + 1280 + hkv * 64 + c0;
  us8 o0, o1;
#pragma unroll
  for (int t = 0; t < 8; ++t) { o0[t] = f2bf(src[t]); o1[t] = f2bf(src[8 + t]); }
  *(us8*)&t_[sl * 72 + c0] = o0;
  *(us8*)&t_[sl * 72 + c0 + 8] = o1;
  __syncthreads();
  const int d = tid >> 2;
  const int sc_ = (tid & 3) * 16;
  us8 w0, w1;
#pragma unroll
  for (int t = 0; t < 8; ++t) w0[t] = t_[(sc_ + t) * 72 + d];
#pragma unroll
  for (int t = 0; t < 8; ++t) w1[t] = t_[(sc_ + 8 + t) * 72 + d];
  unsigned short* dst = vt + (size_t)bkv * 131072 + (size_t)d * 2048 + s0 + sc_;
  *(us8*)dst = w0;
  *(us8*)(dst + 8) = w1;
}

// ---------------------------------------------------------------------------
// Kernel C phase 1: gated causal flash attention, SPLIT-K two-phase.
// Fixed-max softmax makes partial O and l LINEAR in the key set, so each
// (bh,qx) q-tile is split into two key-range halves (2048 items, max 16
// tiles each). 1536 persistent workers (6 blocks/CU = the LDS limit) pop
// items descending-by-size (LPT greedy; makespan ~ mean+eps under any
// dispatch->CU mapping). Unnormalized O (bf16) and l (f32) go to opart/lpart.
// Item t: u=t>>5, bh=t&31, qx=31-(u>>1), half=u&1 (sizes monotone non-incr).
// ---------------------------------------------------------------------------
__global__ __launch_bounds__(256) void attn_kernel(
    const unsigned short* __restrict__ qh, const unsigned short* __restrict__ kh,
    const unsigned short* __restrict__ vt, const unsigned short* __restrict__ qsp,
    const unsigned short* __restrict__ ksp, int* __restrict__ ctr,
    unsigned short* __restrict__ opart, float* __restrict__ lpart) {
  __shared__ unsigned short Ks[64 * 64];
  __shared__ unsigned short Vs[64 * 64];
  __shared__ unsigned short Ksp[64 * 16];
  __shared__ unsigned short Pw[4][16 * 64];
  __shared__ int item_s;

  const int tid = threadIdx.x;
  const int w = tid >> 6;
  const int lane = tid & 63;
  const int nm = lane & 15;
  const int quad = lane >> 4;

  int srow_[2], scol_[2];
#pragma unroll
  for (int rd = 0; rd < 2; ++rd) {
    int Lc = rd * 256 + w * 64 + lane;
    int r = Lc >> 3;
    srow_[rd] = r;
    scol_[rd] = ((Lc & 7) ^ (r & 7)) * 8;
  }
  unsigned short* pw = &Pw[w][0];

  for (;;) {
    if (tid == 0) item_s = atomicAdd(ctr, 1);
    __syncthreads();
    const int t = item_s;
    if (t >= 2048) break;
    const int u = t >> 5;
    const int bh = t & 31;
    const int qx = 31 - (u >> 1);
    const int half = u & 1;
    const int b = bh >> 4, h = bh & 15;
    const int hkv = h >> 2;
    const size_t kbase = (size_t)(b * 4 + hkv) * 2048 * 64;
    const size_t vbase = (size_t)(b * 4 + hkv) * 131072;
    const size_t kspb = (size_t)(b * 4 + hkv) * 2048 * 16;
    const int q0 = qx * 64;
    const int qrow0 = q0 + w * 16;
    const int nt = qx + 1;
    const int hsplit = (nt + 1) >> 1;
    const int jt0 = half ? hsplit : 0;
    const int jt1 = half ? nt : hsplit;

    const size_t qb = ((size_t)(b * 16 + h) * 2048 + qrow0 + nm) * 64;
    bf16x8 qa0 = *(const bf16x8*)(qh + qb + quad * 8);
    bf16x8 qa1 = *(const bf16x8*)(qh + qb + 32 + quad * 8);
    bf16x8 qspa = {0, 0, 0, 0, 0, 0, 0, 0};
    if (quad < 2)
      qspa = *(const bf16x8*)(qsp + ((size_t)(b * 16 + h) * 2048 + qrow0 + nm) * 16 + quad * 8);

    float l_r[4] = {0.f, 0.f, 0.f, 0.f};
    f32x4 O[4] = {{0.f, 0.f, 0.f, 0.f}, {0.f, 0.f, 0.f, 0.f},
                  {0.f, 0.f, 0.f, 0.f}, {0.f, 0.f, 0.f, 0.f}};

    for (int jt = jt0; jt < jt1; ++jt) {
      const int j0 = jt * 64;
      __syncthreads();   // prior tile consumed by all waves
#pragma unroll
      for (int rd = 0; rd < 2; ++rd) {
        gload16(kh + kbase + (size_t)(j0 + srow_[rd]) * 64 + scol_[rd],
                &Ks[(rd * 256 + w * 64) * 8]);
        gload16(vt + vbase + (size_t)srow_[rd] * 2048 + j0 + scol_[rd],
                &Vs[(rd * 256 + w * 64) * 8]);
      }
      if (w < 2) {
        const int Lc = w * 64 + lane;
        gload16(ksp + kspb + (size_t)(j0 + (Lc >> 1)) * 16 + (Lc & 1) * 8,
                &Ksp[w * 512]);
      }
      __syncthreads();   // DMA drained + visible

      // ---- QK^T + gate -> p = exp2(s'*gate), accumulate l, write P ----
      const bool needmask = (j0 + 63 > qrow0);
#pragma unroll
      for (int st = 0; st < 4; ++st) {
        const int krow = st * 16 + nm;
        const int r7 = krow & 7;
        bf16x8 kb0 = *(const bf16x8*)&Ks[(krow * 8 + (quad ^ r7)) * 8];
        bf16x8 kb1 = *(const bf16x8*)&Ks[(krow * 8 + ((4 + quad) ^ r7)) * 8];
        bf16x8 gb = *(const bf16x8*)&Ksp[(krow * 2 + (quad & 1)) * 8];
        f32x4 z = {0.f, 0.f, 0.f, 0.f};
        f32x4 s = __builtin_amdgcn_mfma_f32_16x16x32_bf16(qa0, kb0, z, 0, 0, 0);
        s = __builtin_amdgcn_mfma_f32_16x16x32_bf16(qa1, kb1, s, 0, 0, 0);
        f32x4 g = __builtin_amdgcn_mfma_f32_16x16x32_bf16(qspa, gb, z, 0, 0, 0);
#pragma unroll
        for (int r = 0; r < 4; ++r) {
          float gate = 1.f / (1.f + exp2f(-g[r]));   // g pre-scaled by log2e
          float v = s[r] * gate;                     // s pre-scaled by log2e
          if (needmask) {
            const int col = j0 + st * 16 + nm;
            const int rowg = qrow0 + quad * 4 + r;
            v = (col > rowg) ? -INFINITY : v;
          }
          float p = exp2f(v);        // exp2(-inf) == 0 handles the mask
          l_r[r] += p;
          const int prow = quad * 4 + r;
          const int chunk = (st * 2 + (nm >> 3)) ^ (prow & 7);
          pw[(prow * 8 + chunk) * 8 + (nm & 7)] = f2bf(p);
        }
      }

      // ---- PV: P (A-frag) x V^T rows (B-frag) ----
#pragma unroll
      for (int c = 0; c < 2; ++c) {
        const int gc = c * 4 + quad;
        bf16x8 pa = *(const bf16x8*)&pw[(nm * 8 + (gc ^ (nm & 7))) * 8];
#pragma unroll
        for (int dt = 0; dt < 4; ++dt) {
          const int vrow = dt * 16 + nm;
          bf16x8 vb = *(const bf16x8*)&Vs[(vrow * 8 + (gc ^ (vrow & 7))) * 8];
          O[dt] = __builtin_amdgcn_mfma_f32_16x16x32_bf16(pa, vb, O[dt], 0, 0, 0);
        }
      }
    }

    // ---- epilogue: write UNNORMALIZED partial O (bf16) + reduced l ----
#pragma unroll
    for (int r = 0; r < 4; ++r) {
      float v = l_r[r];
      v += __shfl_xor(v, 1);
      v += __shfl_xor(v, 2);
      v += __shfl_xor(v, 4);
      v += __shfl_xor(v, 8);
      const int prow = w * 16 + quad * 4 + r;
      unsigned short* orow = opart + ((size_t)t * 64 + prow) * 64 + nm;
#pragma unroll
      for (int dt = 0; dt < 4; ++dt) orow[dt * 16] = f2bf(O[dt][r]);
      if (nm == 0) lpart[t * 64 + prow] = v;
    }
  }
}

// ---------------------------------------------------------------------------
// Kernel C phase 2: combine split-K halves: O=(O0+O1)/(l0+l1) -> bf16 ao.
// Grid (bh=32, qx=32); item part index for (bh,qx,half): ((31-qx)*2+half)*32+bh.
// ---------------------------------------------------------------------------
__global__ __launch_bounds__(256) void attn_combine(
    const unsigned short* __restrict__ opart, const float* __restrict__ lpart,
    unsigned short* __restrict__ ao) {
  const int bh = blockIdx.x, qx = blockIdx.y;
  const int b = bh >> 4, h = bh & 15;
  const int t = threadIdx.x;
  const int row = t >> 2, d0 = (t & 3) * 16;
  const size_t p0 = (size_t)((31 - qx) * 2) * 32 + bh;
  const size_t p1 = p0 + 32;
  const unsigned short* a0 = opart + (p0 * 64 + row) * 64 + d0;
  const unsigned short* a1 = opart + (p1 * 64 + row) * 64 + d0;
  const float inv = 1.f / (lpart[p0 * 64 + row] + lpart[p1 * 64 + row]);
  us8 x0 = *(const us8*)a0;
  us8 x1 = *(const us8*)(a0 + 8);
  us8 y0 = *(const us8*)a1;
  us8 y1 = *(const us8*)(a1 + 8);
  us8 o0, o1;
#pragma unroll
  for (int i = 0; i < 8; ++i) {
    o0[i] = f2bf((bf2f(x0[i]) + bf2f(y0[i])) * inv);
    o1[i] = f2bf((bf2f(x1[i]) + bf2f(y1[i])) * inv);
  }
  unsigned short* dst = ao + ((size_t)b * 2048 + qx * 64 + row) * 1024 + h * 64 + d0;
  *(us8*)dst = o0;
  *(us8*)(dst + 8) = o1;
}

// ---------------------------------------------------------------------------
extern "C" void kernel_launch(void* const* d_in, const int* in_sizes, int n_in,
                              void* d_out, int out_size, void* d_ws,
                              size_t ws_size, hipStream_t stream) {
  const float* x = (const float*)d_in[0];
  const float* Wq = (const float*)d_in[1];
  const float* Wk = (const float*)d_in[2];
  const float* Wv = (const float*)d_in[3];
  const float* Wo = (const float*)d_in[4];
  const float* bo = (const float*)d_in[5];
  const float* Ws = (const float*)d_in[6];
  const float* bs = (const float*)d_in[7];
  float* out = (float*)d_out;

  // Workspace layout (bytes):
  char* wsb = (char*)d_ws;
  float* proj = (float*)wsb;                                  // 25,165,824 B (dead after rope/vt)
  unsigned short* aob  = (unsigned short*)wsb;                // 8,388,608 B (alias proj head)
  unsigned short* opart = (unsigned short*)(wsb + 8388608);   // 16,777,216 B (alias proj tail)
  unsigned short* qh   = (unsigned short*)(wsb + 25165824);   // 8,388,608 B
  unsigned short* kh   = (unsigned short*)(wsb + 33554432);   // 2,097,152 B
  unsigned short* vtb  = (unsigned short*)(wsb + 35651584);   // 2,097,152 B
  unsigned short* qsp  = (unsigned short*)(wsb + 37748736);   // 2,097,152 B
  unsigned short* ksp  = (unsigned short*)(wsb + 39845888);   //   524,288 B
  unsigned short* xb   = (unsigned short*)(wsb + 40370176);   // 8,388,608 B (dead after qkv gemm)
  float* lpart         = (float*)(wsb + 40370176);            //   524,288 B (alias xb)
  unsigned short* wqkv = (unsigned short*)(wsb + 48758784);   // 3,145,728 B
  unsigned short* wob  = (unsigned short*)(wsb + 51904512);   // 2,097,152 B
  int* ctr             = (int*)(wsb + 54001664);              //         4 B

  convert_bf16<<<dim3(3328), 256, 0, stream>>>(x, Wq, Wk, Wv, Wo, xb, wqkv, wob, ctr);
  gemm_bf16<<<dim3(12, 64), 256, 0, stream>>>(xb, wqkv, nullptr, proj, 1536);
  rope_scatter<<<dim3(4096), 256, 0, stream>>>(proj, Ws, bs, qh, kh, qsp, ksp);
  v_transpose<<<dim3(32, 8), 256, 0, stream>>>(proj, vtb);
  attn_kernel<<<dim3(1536), 256, 0, stream>>>(qh, kh, vtb, qsp, ksp, ctr, opart, lpart);
  attn_combine<<<dim3(32, 32), 256, 0, stream>>>(opart, lpart, aob);
  gemm_bf16<<<dim3(8, 64), 256, 0, stream>>>(aob, wob, bo, out, 1024);
}

// Round 9
// 222.252 us; speedup vs baseline: 1.0742x; 1.0742x over previous
//
#include <hip/hip_runtime.h>
#include <math.h>

// Problem constants
#define B_ 2
#define S_ 2048
#define D_ 1024
#define H_ 16
#define HKV_ 4
#define HD_ 64
#define SD_ 16

typedef __attribute__((ext_vector_type(8))) short bf16x8;
typedef __attribute__((ext_vector_type(4))) float f32x4;
typedef __attribute__((ext_vector_type(8))) unsigned short us8;
typedef __attribute__((ext_vector_type(4))) unsigned short us4;

#define LOG2E 1.4426950408889634f

__device__ __forceinline__ unsigned short f2bf(float f) {
  unsigned int u = __builtin_bit_cast(unsigned int, f);
  u += 0x7fffu + ((u >> 16) & 1u);   // RNE; inputs are finite
  return (unsigned short)(u >> 16);
}

// global -> LDS async DMA, 16B per lane; LDS dest wave-uniform base + lane*16.
__device__ __forceinline__ void gload16(const unsigned short* g, unsigned short* l) {
  __builtin_amdgcn_global_load_lds(
      (const __attribute__((address_space(1))) unsigned int*)g,
      (__attribute__((address_space(3))) unsigned int*)l, 16, 0, 0);
}

// ---------------------------------------------------------------------------
// Kernel 0: fp32 -> bf16 convert for GEMM operands. Also zeroes the attn
// work-stealing counter (runs first on the stream; re-zeroed every launch).
// ---------------------------------------------------------------------------
__global__ __launch_bounds__(256) void convert_bf16(
    const float* __restrict__ x, const float* __restrict__ wq,
    const float* __restrict__ wk, const float* __restrict__ wv,
    const float* __restrict__ wo, unsigned short* __restrict__ xb,
    unsigned short* __restrict__ wqkv, unsigned short* __restrict__ wob,
    int* __restrict__ ctr) {
  const int blk = blockIdx.x;
  if (blk == 0 && threadIdx.x == 0) *ctr = 0;
  const float* src;
  unsigned short* dst;
  int off;
  if (blk < 2048)      { src = x;  dst = xb;             off = blk * 2048; }
  else if (blk < 2560) { src = wq; dst = wqkv;           off = (blk - 2048) * 2048; }
  else if (blk < 2688) { src = wk; dst = wqkv + 1048576; off = (blk - 2560) * 2048; }
  else if (blk < 2816) { src = wv; dst = wqkv + 1310720; off = (blk - 2688) * 2048; }
  else                 { src = wo; dst = wob;            off = (blk - 2816) * 2048; }
  const int i = off + threadIdx.x * 8;
  float4 a = *(const float4*)(src + i);
  float4 b = *(const float4*)(src + i + 4);
  us8 o;
  o[0] = f2bf(a.x); o[1] = f2bf(a.y); o[2] = f2bf(a.z); o[3] = f2bf(a.w);
  o[4] = f2bf(b.x); o[5] = f2bf(b.y); o[6] = f2bf(b.z); o[7] = f2bf(b.w);
  *(us8*)(dst + i) = o;
}

// ---------------------------------------------------------------------------
// Kernel A/D: bf16 MFMA GEMM, m97 staging, 64x128 tile.
// ---------------------------------------------------------------------------
__global__ __launch_bounds__(256) void gemm_bf16(
    const unsigned short* __restrict__ A, const unsigned short* __restrict__ Bm,
    const float* __restrict__ bias, float* __restrict__ C, int N) {
  __shared__ unsigned short As[64 * 64];
  __shared__ unsigned short Bs[128 * 64];
  const int tid = threadIdx.x;
  const int w = tid >> 6, lane = tid & 63;
  const int nm = lane & 15, quad = lane >> 4;
  const int m0 = blockIdx.y * 64, n0 = blockIdx.x * 128;
  const int wn = w * 32;

  f32x4 acc[4][2] = {};
  int arow[2], acol[2], brow[4], bcol[4];
#pragma unroll
  for (int it = 0; it < 2; ++it) {
    int s = it * 256 + tid;
    arow[it] = s >> 3;
    acol[it] = ((s & 7) ^ (arow[it] & 7)) * 8;
  }
#pragma unroll
  for (int it = 0; it < 4; ++it) {
    int s = it * 256 + tid;
    brow[it] = s >> 3;
    bcol[it] = ((s & 7) ^ (brow[it] & 7)) * 8;
  }

  for (int k0 = 0; k0 < 1024; k0 += 64) {
    __syncthreads();
#pragma unroll
    for (int it = 0; it < 2; ++it)
      gload16(A + (size_t)(m0 + arow[it]) * 1024 + k0 + acol[it],
              &As[(it * 256 + w * 64) * 8]);
#pragma unroll
    for (int it = 0; it < 4; ++it)
      gload16(Bm + (size_t)(n0 + brow[it]) * 1024 + k0 + bcol[it],
              &Bs[(it * 256 + w * 64) * 8]);
    __syncthreads();

#pragma unroll
    for (int ks = 0; ks < 2; ++ks) {
      const int cq = ks * 4 + quad;
      bf16x8 af[4], bfr[2];
#pragma unroll
      for (int mi = 0; mi < 4; ++mi) {
        const int m = mi * 16 + nm;
        af[mi] = *(const bf16x8*)&As[(m * 8 + (cq ^ (m & 7))) * 8];
      }
#pragma unroll
      for (int ni = 0; ni < 2; ++ni) {
        const int n = wn + ni * 16 + nm;
        bfr[ni] = *(const bf16x8*)&Bs[(n * 8 + (cq ^ (n & 7))) * 8];
      }
#pragma unroll
      for (int mi = 0; mi < 4; ++mi)
#pragma unroll
        for (int ni = 0; ni < 2; ++ni)
          acc[mi][ni] = __builtin_amdgcn_mfma_f32_16x16x32_bf16(
              af[mi], bfr[ni], acc[mi][ni], 0, 0, 0);
    }
  }

  float bv[2] = {0.f, 0.f};
  if (bias) {
#pragma unroll
    for (int ni = 0; ni < 2; ++ni) bv[ni] = bias[n0 + wn + ni * 16 + nm];
  }
#pragma unroll
  for (int mi = 0; mi < 4; ++mi) {
#pragma unroll
    for (int r = 0; r < 4; ++r) {
      const int row = m0 + mi * 16 + quad * 4 + r;
      float* crow = C + (size_t)row * N + n0 + wn + nm;
#pragma unroll
      for (int ni = 0; ni < 2; ++ni) crow[ni * 16] = acc[mi][ni][r] + bv[ni];
    }
  }
}

// ---------------------------------------------------------------------------
// Kernel B: RoPE + scatter (bf16) + low-rank sparsity proj (slots 0..19).
// q scaled by log2e/8, qsp by log2e/4 so attn uses native exp2.
// ---------------------------------------------------------------------------
__global__ __launch_bounds__(256) void rope_scatter(
    const float* __restrict__ P, const float* __restrict__ Ws,
    const float* __restrict__ bs, unsigned short* __restrict__ qh,
    unsigned short* __restrict__ kh, unsigned short* __restrict__ qsp,
    unsigned short* __restrict__ ksp) {
  __shared__ float wsl[16 * 64];
  __shared__ float bsl[16];
  __shared__ float rbuf[4][64];
  const int tid = threadIdx.x;
  const int row = blockIdx.x;
  const int b = row >> 11;
  const int s = row & 2047;
  {
    *(float4*)&wsl[tid * 4] = *(const float4*)&Ws[tid * 4];
    if (tid < 16) bsl[tid] = bs[tid];
  }
  __syncthreads();
  const int w = tid >> 6, lane = tid & 63;
  const int i = lane & 31, halfu = lane >> 5;
  const float theta = powf(10000.f, -((float)(2 * i) * (1.f / 64.f)));
  const float f = (float)s * theta;
  const float cf = cosf(f);
  const float sf = sinf(f);
  for (int slot = w; slot < 20; slot += 4) {
    float val = P[(size_t)row * 1536 + slot * 64 + lane];
    float partner = __shfl_xor(val, 32);
    float rot = halfu ? partner : -partner;
    float r = val * cf + rot * sf;
    unsigned short* dst;
    unsigned short* spdst;
    float qscale, spscale;
    if (slot < 16) {
      dst = qh + ((size_t)(b * 16 + slot) * 2048 + s) * 64;
      spdst = qsp + ((size_t)(b * 16 + slot) * 2048 + s) * 16;
      qscale = 0.125f * LOG2E; spscale = 0.25f * LOG2E;
    } else {
      int hh = slot - 16;
      dst = kh + ((size_t)(b * 4 + hh) * 2048 + s) * 64;
      spdst = ksp + ((size_t)(b * 4 + hh) * 2048 + s) * 16;
      qscale = 1.f; spscale = 1.f;
    }
    dst[lane] = f2bf(r * qscale);
    rbuf[w][lane] = r;
    int p = lane >> 4, j = lane & 15;
    float partial = 0.f;
#pragma unroll
    for (int t = 0; t < 16; ++t)
      partial += wsl[j * 64 + p * 16 + t] * rbuf[w][p * 16 + t];
    partial += __shfl_xor(partial, 16);
    partial += __shfl_xor(partial, 32);
    if (p == 0) spdst[j] = f2bf((partial + bsl[j]) * spscale);
  }
}

// ---------------------------------------------------------------------------
// Kernel B2: one-time V transpose: proj v-cols (f32) -> vt[bkv][d=64][s=2048] bf16.
// ---------------------------------------------------------------------------
__global__ __launch_bounds__(256) void v_transpose(
    const float* __restrict__ proj, unsigned short* __restrict__ vt) {
  __shared__ unsigned short t_[64 * 72];
  const int bkv = blockIdx.y;
  const int s0 = blockIdx.x * 64;
  const int b = bkv >> 2, hkv = bkv & 3;
  const int tid = threadIdx.x;
  const int sl = tid >> 2;
  const int c0 = (tid & 3) * 16;
  const float* src = proj + ((size_t)b * 2048 + s0 + sl) * 1536 + 1280 + hkv * 64 + c0;
  us8 o0, o1;
#pragma unroll
  for (int t = 0; t < 8; ++t) { o0[t] = f2bf(src[t]); o1[t] = f2bf(src[8 + t]); }
  *(us8*)&t_[sl * 72 + c0] = o0;
  *(us8*)&t_[sl * 72 + c0 + 8] = o1;
  __syncthreads();
  const int d = tid >> 2;
  const int sc_ = (tid & 3) * 16;
  us8 w0, w1;
#pragma unroll
  for (int t = 0; t < 8; ++t) w0[t] = t_[(sc_ + t) * 72 + d];
#pragma unroll
  for (int t = 0; t < 8; ++t) w1[t] = t_[(sc_ + 8 + t) * 72 + d];
  unsigned short* dst = vt + (size_t)bkv * 131072 + (size_t)d * 2048 + s0 + sc_;
  *(us8*)dst = w0;
  *(us8*)(dst + 8) = w1;
}

// ---------------------------------------------------------------------------
// Kernel C: gated causal flash attention. R9: 512 blocks x 512 threads
// (8 waves). Wave w = (key-half kh2 = w>>2, q-group qg = w&3). Each block
// pops single-q-tile items (1024 items, descending size 32..1) from a global
// counter: 2.0 items/worker -> LPT makespan ~34 vs 33 ideal, under ANY
// dispatch->CU mapping; uniform 8 waves/block -> 16 waves/CU at 2 blocks/CU.
// Per staged 64-key tile each wave computes its 16q x 32k quarter (half the
// MFMA/VALU of R8's wave-tile). Fixed-max softmax => O,l linear in keys:
// key-halves combined once per item via LDS (K/V region reused as scratch).
// ---------------------------------------------------------------------------
__global__ __launch_bounds__(512) void attn_kernel(
    const unsigned short* __restrict__ qh, const unsigned short* __restrict__ kh,
    const unsigned short* __restrict__ vt, const unsigned short* __restrict__ qsp,
    const unsigned short* __restrict__ ksp, int* __restrict__ ctr,
    unsigned short* __restrict__ ao) {
  __shared__ unsigned short KV[2][64 * 64];   // [0]=K (keys x d), [1]=V^T (d x keys)
  __shared__ unsigned short Ksp[64 * 16];
  __shared__ unsigned short Pw[8][16 * 32];   // per-wave P: 16q x 32k
  __shared__ int item_s;

  const int tid = threadIdx.x;
  const int w = tid >> 6;
  const int lane = tid & 63;
  const int nm = lane & 15;
  const int quad = lane >> 4;
  const int kh2 = w >> 2;         // key half: keys kh2*32 .. +31 of each tile
  const int qg = w & 3;           // q-row group: rows qg*16 .. +15 of the q-tile

  // staging decode: 512 lanes cover the 512 16B chunks of Ks and of Vs
  const int r_ = tid >> 3;                  // row 0..63
  const int gc_ = ((tid & 7) ^ (r_ & 7));   // XOR-swizzled global chunk
  unsigned short* pw = &Pw[w][0];

  for (;;) {
    if (tid == 0) item_s = atomicAdd(ctr, 1);
    __syncthreads();
    const int t = item_s;
    if (t >= 1024) break;
    const int qx = 31 - (t >> 5);      // descending work: 32,31,...,1 tiles
    const int bh = t & 31;
    const int b = bh >> 4, h = bh & 15;
    const int hkv = h >> 2;
    const size_t kbase = (size_t)(b * 4 + hkv) * 2048 * 64;
    const size_t vbase = (size_t)(b * 4 + hkv) * 131072;
    const size_t kspb = (size_t)(b * 4 + hkv) * 2048 * 16;
    const int qrow0 = qx * 64 + qg * 16;

    const size_t qb = ((size_t)(b * 16 + h) * 2048 + qrow0 + nm) * 64;
    bf16x8 qa0 = *(const bf16x8*)(qh + qb + quad * 8);
    bf16x8 qa1 = *(const bf16x8*)(qh + qb + 32 + quad * 8);
    bf16x8 qspa = {0, 0, 0, 0, 0, 0, 0, 0};
    if (quad < 2)
      qspa = *(const bf16x8*)(qsp + ((size_t)(b * 16 + h) * 2048 + qrow0 + nm) * 16 + quad * 8);

    float l_r[4] = {0.f, 0.f, 0.f, 0.f};
    f32x4 O[4] = {{0.f, 0.f, 0.f, 0.f}, {0.f, 0.f, 0.f, 0.f},
                  {0.f, 0.f, 0.f, 0.f}, {0.f, 0.f, 0.f, 0.f}};

    const int ntile = qx + 1;
    for (int jt = 0; jt < ntile; ++jt) {
      const int j0 = jt * 64;
      __syncthreads();   // prior tile + epilogue scratch fully consumed
      gload16(kh + kbase + (size_t)(j0 + r_) * 64 + gc_ * 8, &KV[0][w * 512]);
      gload16(vt + vbase + (size_t)r_ * 2048 + j0 + gc_ * 8, &KV[1][w * 512]);
      if (w < 2)
        gload16(ksp + kspb + (size_t)(j0 + (tid >> 1)) * 16 + (tid & 1) * 8,
                &Ksp[w * 512]);
      __syncthreads();   // DMA drained + visible

      // ---- QK^T + gate for this wave's 16q x 32k quarter ----
#pragma unroll
      for (int st2 = 0; st2 < 2; ++st2) {
        const int kcol0 = kh2 * 32 + st2 * 16;
        if (j0 + kcol0 > qrow0 + 15) {
          // fully-masked key group on the diagonal tile: P must be zero
#pragma unroll
          for (int r = 0; r < 4; ++r) {
            const int prow = quad * 4 + r;
            const int chunk = (st2 * 2 + (nm >> 3)) ^ (prow & 3);
            pw[(prow * 4 + chunk) * 8 + (nm & 7)] = 0;
          }
          continue;
        }
        const int krow = kcol0 + nm;
        const int r7 = krow & 7;
        bf16x8 kb0 = *(const bf16x8*)&KV[0][(krow * 8 + (quad ^ r7)) * 8];
        bf16x8 kb1 = *(const bf16x8*)&KV[0][(krow * 8 + ((4 + quad) ^ r7)) * 8];
        bf16x8 gb = *(const bf16x8*)&Ksp[(krow * 2 + (quad & 1)) * 8];
        f32x4 z = {0.f, 0.f, 0.f, 0.f};
        f32x4 s = __builtin_amdgcn_mfma_f32_16x16x32_bf16(qa0, kb0, z, 0, 0, 0);
        s = __builtin_amdgcn_mfma_f32_16x16x32_bf16(qa1, kb1, s, 0, 0, 0);
        f32x4 g = __builtin_amdgcn_mfma_f32_16x16x32_bf16(qspa, gb, z, 0, 0, 0);
        const bool needmask = (j0 + kcol0 + 15 > qrow0);
#pragma unroll
        for (int r = 0; r < 4; ++r) {
          float gate = 1.f / (1.f + exp2f(-g[r]));   // g pre-scaled by log2e
          float v = s[r] * gate;                     // s pre-scaled by log2e
          if (needmask) {
            const int col = j0 + kcol0 + nm;
            const int rowg = qrow0 + quad * 4 + r;
            v = (col > rowg) ? -INFINITY : v;
          }
          float p = exp2f(v);        // exp2(-inf) == 0 handles the mask
          l_r[r] += p;
          const int prow = quad * 4 + r;
          const int chunk = (st2 * 2 + (nm >> 3)) ^ (prow & 3);
          pw[(prow * 4 + chunk) * 8 + (nm & 7)] = f2bf(p);
        }
      }

      // ---- PV: P (A-frag, one b128/lane) x V^T rows (B-frag), K=32 ----
      {
        bf16x8 pa = *(const bf16x8*)&pw[(nm * 4 + (quad ^ (nm & 3))) * 8];
#pragma unroll
        for (int dt = 0; dt < 4; ++dt) {
          const int vrow = dt * 16 + nm;
          const int gvc = kh2 * 4 + quad;
          bf16x8 vb = *(const bf16x8*)&KV[1][(vrow * 8 + (gvc ^ (vrow & 7))) * 8];
          O[dt] = __builtin_amdgcn_mfma_f32_16x16x32_bf16(pa, vb, O[dt], 0, 0, 0);
        }
      }
    }

    // ---- epilogue: combine key-halves via LDS, normalize, store bf16 ----
    __syncthreads();                       // staged tile data now dead
    float* osc = (float*)&KV[0][0];        // 64q x 64d f32 (16 KB)
    float* lsc = (float*)&Pw[0][0];        // 64q x 16 f32 (4 KB)
    if (kh2 == 1) {
#pragma unroll
      for (int r = 0; r < 4; ++r) {
        const int prow = qg * 16 + quad * 4 + r;
#pragma unroll
        for (int dt = 0; dt < 4; ++dt)
          osc[prow * 64 + dt * 16 + nm] = O[dt][r];
        lsc[prow * 16 + nm] = l_r[r];
      }
    }
    __syncthreads();
    if (kh2 == 0) {
#pragma unroll
      for (int r = 0; r < 4; ++r) {
        const int prow = qg * 16 + quad * 4 + r;
        float lv = l_r[r] + lsc[prow * 16 + nm];
        lv += __shfl_xor(lv, 1);
        lv += __shfl_xor(lv, 2);
        lv += __shfl_xor(lv, 4);
        lv += __shfl_xor(lv, 8);
        const float inv = 1.f / lv;
        const int rowg = qx * 64 + prow;
        unsigned short* orow = ao + ((size_t)b * 2048 + rowg) * 1024 + h * 64 + nm;
#pragma unroll
        for (int dt = 0; dt < 4; ++dt)
          orow[dt * 16] = f2bf((O[dt][r] + osc[prow * 64 + dt * 16 + nm]) * inv);
      }
    }
  }
}

// ---------------------------------------------------------------------------
extern "C" void kernel_launch(void* const* d_in, const int* in_sizes, int n_in,
                              void* d_out, int out_size, void* d_ws,
                              size_t ws_size, hipStream_t stream) {
  const float* x = (const float*)d_in[0];
  const float* Wq = (const float*)d_in[1];
  const float* Wk = (const float*)d_in[2];
  const float* Wv = (const float*)d_in[3];
  const float* Wo = (const float*)d_in[4];
  const float* bo = (const float*)d_in[5];
  const float* Ws = (const float*)d_in[6];
  const float* bs = (const float*)d_in[7];
  float* out = (float*)d_out;

  // Workspace layout (bytes):
  char* wsb = (char*)d_ws;
  float* proj = (float*)wsb;                                  // 25,165,824 B (dead after rope/vt)
  unsigned short* aob  = (unsigned short*)wsb;                // 8,388,608 B (alias proj head)
  unsigned short* qh   = (unsigned short*)(wsb + 25165824);   // 8,388,608 B
  unsigned short* kh   = (unsigned short*)(wsb + 33554432);   // 2,097,152 B
  unsigned short* vtb  = (unsigned short*)(wsb + 35651584);   // 2,097,152 B
  unsigned short* qsp  = (unsigned short*)(wsb + 37748736);   // 2,097,152 B
  unsigned short* ksp  = (unsigned short*)(wsb + 39845888);   //   524,288 B
  unsigned short* xb   = (unsigned short*)(wsb + 40370176);   // 8,388,608 B
  unsigned short* wqkv = (unsigned short*)(wsb + 48758784);   // 3,145,728 B
  unsigned short* wob  = (unsigned short*)(wsb + 51904512);   // 2,097,152 B
  int* ctr             = (int*)(wsb + 54001664);              //         4 B

  convert_bf16<<<dim3(3328), 256, 0, stream>>>(x, Wq, Wk, Wv, Wo, xb, wqkv, wob, ctr);
  gemm_bf16<<<dim3(12, 64), 256, 0, stream>>>(xb, wqkv, nullptr, proj, 1536);
  rope_scatter<<<dim3(4096), 256, 0, stream>>>(proj, Ws, bs, qh, kh, qsp, ksp);
  v_transpose<<<dim3(32, 8), 256, 0, stream>>>(proj, vtb);
  attn_kernel<<<dim3(512), 512, 0, stream>>>(qh, kh, vtb, qsp, ksp, ctr, aob);
  gemm_bf16<<<dim3(8, 64), 256, 0, stream>>>(aob, wob, bo, out, 1024);
}